// Round 3
// baseline (4673.400 us; speedup 1.0000x reference)
//
#include <hip/hip_runtime.h>
#include <hip/hip_bf16.h>
#include <math.h>

typedef __attribute__((ext_vector_type(8))) short short8;
typedef __attribute__((ext_vector_type(4))) float floatx4;

__device__ __forceinline__ float sigmoidf_(float v){ return 1.f/(1.f+expf(-v)); }

__device__ __forceinline__ floatx4 mfma16(short8 a, short8 b, floatx4 c) {
    return __builtin_amdgcn_mfma_f32_16x16x32_bf16(a, b, c, 0, 0, 0);
}

// split-bf16 store: v -> [hi | lo | hi] planes of a tripled-K activation row
__device__ __forceinline__ void store3(__hip_bfloat16* p, long row, int kp, int col, float v){
    __hip_bfloat16 hi = __float2bfloat16(v);
    float lo = v - __bfloat162float(hi);
    p[row + col]        = hi;
    p[row + kp + col]   = __float2bfloat16(lo);
    p[row + 2*kp + col] = hi;
}

// ===========================================================================
// MFMA mainloop: C-tile 32m x 128n, 256 threads (4 waves).
// K processed in 64-elem iters (2 x 32-K substeps per barrier pair), register
// prefetch depth = 2 iters. sA = 4KB, sB = 16KB.
// ===========================================================================
#define MFMA_TILE_BODY \
    { const short8* A8 = (const short8*)sA; \
      const short8* B8 = (const short8*)sB; \
      short8 a0 = A8[l], a1 = A8[64+l]; \
      short8 b0 = B8[(w*2)*64 + l], b1 = B8[(w*2+1)*64 + l]; \
      acc[0][0] = mfma16(a0,b0,acc[0][0]); \
      acc[0][1] = mfma16(a0,b1,acc[0][1]); \
      acc[1][0] = mfma16(a1,b0,acc[1][0]); \
      acc[1][1] = mfma16(a1,b1,acc[1][1]); }

#define MFMA_TILE_BODY2 \
    { const short8* A8 = (const short8*)sA; \
      const short8* B8 = (const short8*)sB; \
      short8 a0 = A8[l], a1 = A8[64+l]; \
      short8 b0 = B8[(w*2)*64 + l], b1 = B8[(w*2+1)*64 + l]; \
      acc[0][0] = mfma16(a0,b0,acc[0][0]); \
      acc[0][1] = mfma16(a0,b1,acc[0][1]); \
      acc[1][0] = mfma16(a1,b0,acc[1][0]); \
      acc[1][1] = mfma16(a1,b1,acc[1][1]); \
      short8 c0 = A8[128+l], c1 = A8[192+l]; \
      short8 d0 = B8[512+(w*2)*64 + l], d1 = B8[512+(w*2+1)*64 + l]; \
      acc[0][0] = mfma16(c0,d0,acc[0][0]); \
      acc[0][1] = mfma16(c0,d1,acc[0][1]); \
      acc[1][0] = mfma16(c1,d0,acc[1][0]); \
      acc[1][1] = mfma16(c1,d1,acc[1][1]); }

__device__ void mfma_loop_32x128(const __hip_bfloat16* Apk, long lda, int m0,
                                 const __hip_bfloat16* Wrows, long ldb,
                                 int KS, char* sA, char* sB, floatx4 acc[2][2])
{
    const int tid = threadIdx.x, l = tid & 63, w = tid >> 6;
    const char* Ab = (const char*)(Apk + (long)(m0 + (tid>>6)*16 + (tid&15))*lda
                                   + (long)(((tid&63)>>4)*8));
    int r0 = tid >> 2, qd = tid & 3;
    const char* Bb0 = (const char*)(Wrows + (long)r0*ldb + qd*8);
    const char* Bb1 = (const char*)(Wrows + (long)(r0+64)*ldb + qd*8);
    int4* sAv = (int4*)sA;
    int4* sBv = (int4*)sB;
    int bs0 = (r0>>4)*64 + (r0&15) + (qd<<4);
    int bs1 = bs0 + 256;
    const int NIT = KS >> 1, tail = KS & 1;
    int4 aE0,aE1,b0E0,b0E1,b1E0,b1E1;
    int4 aO0,aO1,b0O0,b0O1,b1O0,b1O1;
    if (NIT > 0) {
        if (tid < 128) { aE0 = *(const int4*)Ab; aE1 = *(const int4*)(Ab+64); }
        b0E0 = *(const int4*)Bb0; b0E1 = *(const int4*)(Bb0+64);
        b1E0 = *(const int4*)Bb1; b1E1 = *(const int4*)(Bb1+64);
    }
    if (NIT > 1) {
        if (tid < 128) { aO0 = *(const int4*)(Ab+128); aO1 = *(const int4*)(Ab+192); }
        b0O0 = *(const int4*)(Bb0+128); b0O1 = *(const int4*)(Bb0+192);
        b1O0 = *(const int4*)(Bb1+128); b1O1 = *(const int4*)(Bb1+192);
    }
    int it = 0;
    for (; it + 1 < NIT; it += 2) {
        // even buffer
        __syncthreads();
        if (tid < 128) { sAv[tid] = aE0; sAv[128+tid] = aE1; }
        sBv[bs0] = b0E0; sBv[bs1] = b1E0; sBv[512+bs0] = b0E1; sBv[512+bs1] = b1E1;
        __syncthreads();
        if (it + 2 < NIT) {
            long off = (long)(it+2)*128;
            if (tid < 128) { aE0 = *(const int4*)(Ab+off); aE1 = *(const int4*)(Ab+off+64); }
            b0E0 = *(const int4*)(Bb0+off); b0E1 = *(const int4*)(Bb0+off+64);
            b1E0 = *(const int4*)(Bb1+off); b1E1 = *(const int4*)(Bb1+off+64);
        }
        MFMA_TILE_BODY2
        // odd buffer
        __syncthreads();
        if (tid < 128) { sAv[tid] = aO0; sAv[128+tid] = aO1; }
        sBv[bs0] = b0O0; sBv[bs1] = b1O0; sBv[512+bs0] = b0O1; sBv[512+bs1] = b1O1;
        __syncthreads();
        if (it + 3 < NIT) {
            long off = (long)(it+3)*128;
            if (tid < 128) { aO0 = *(const int4*)(Ab+off); aO1 = *(const int4*)(Ab+off+64); }
            b0O0 = *(const int4*)(Bb0+off); b0O1 = *(const int4*)(Bb0+off+64);
            b1O0 = *(const int4*)(Bb1+off); b1O1 = *(const int4*)(Bb1+off+64);
        }
        MFMA_TILE_BODY2
    }
    if (it < NIT) {   // NIT odd: final 64-K iter from even buffer
        __syncthreads();
        if (tid < 128) { sAv[tid] = aE0; sAv[128+tid] = aE1; }
        sBv[bs0] = b0E0; sBv[bs1] = b1E0; sBv[512+bs0] = b0E1; sBv[512+bs1] = b1E1;
        __syncthreads();
        MFMA_TILE_BODY2
    }
    if (tail) {       // final 32-K step
        long off = (long)NIT*128;
        int4 aT, bT0, bT1;
        if (tid < 128) aT = *(const int4*)(Ab+off);
        bT0 = *(const int4*)(Bb0+off); bT1 = *(const int4*)(Bb1+off);
        __syncthreads();
        if (tid < 128) sAv[tid] = aT;
        sBv[bs0] = bT0; sBv[bs1] = bT1;
        __syncthreads();
        MFMA_TILE_BODY
    }
}

// ---------------------------------------------------------------------------
// Split-K2 partial handoff: store my acc; ticket; loser sums both and
// continues (returns 1), winner returns 0.
// partial layout: [tile][half][tid*16]  (4096 floats per half)
// ---------------------------------------------------------------------------
__device__ int splitk_handoff(floatx4 acc[2][2], float* partial, int* cnt,
                              int tile, int half)
{
    const int tid = threadIdx.x;
    float* pb = partial + ((long)tile*2 + half)*4096 + tid*16;
    *(floatx4*)(pb)    = acc[0][0];
    *(floatx4*)(pb+4)  = acc[0][1];
    *(floatx4*)(pb+8)  = acc[1][0];
    *(floatx4*)(pb+12) = acc[1][1];
    __threadfence();
    __shared__ int who;
    __syncthreads();
    if (tid == 0) who = atomicAdd(&cnt[tile], 1);
    __syncthreads();
    if (who == 0) return 0;
    __threadfence();
    const float* ob = partial + ((long)tile*2 + (1-half))*4096 + tid*16;
    acc[0][0] += *(const floatx4*)(ob);
    acc[0][1] += *(const floatx4*)(ob+4);
    acc[1][0] += *(const floatx4*)(ob+8);
    acc[1][1] += *(const floatx4*)(ob+12);
    return 1;
}

// Generic 32x128 tile: D = A@W^T + b1 + b2 -> fp32 or bf16 out
__device__ void gemm_tile(const __hip_bfloat16* Apk, long lda, int m0,
                          const __hip_bfloat16* Wpk, long ldb, int n0,
                          const float* b1, const float* b2,
                          void* Cout, long ldc, int KS, int out_bf16, char* smem)
{
    char* sA = smem; char* sB = smem + 4096;
    floatx4 z4 = {0.f,0.f,0.f,0.f};
    floatx4 acc[2][2] = {{z4,z4},{z4,z4}};
    mfma_loop_32x128(Apk, lda, m0, Wpk + (long)n0*ldb, ldb, KS, sA, sB, acc);
    const int tid = threadIdx.x, l = tid&63, w = tid>>6;
    for (int i = 0; i < 2; ++i)
      for (int jn = 0; jn < 2; ++jn) {
        int n = n0 + (w*2+jn)*16 + (l&15);
        float bb = (b1? b1[n]:0.f) + (b2? b2[n]:0.f);
        for (int r = 0; r < 4; ++r) {
            int m = m0 + i*16 + ((l>>4)<<2) + r;
            float v = acc[i][jn][r] + bb;
            if (out_bf16) ((__hip_bfloat16*)Cout)[(long)m*ldc + n] = __float2bfloat16(v);
            else          ((float*)Cout)[(long)m*ldc + n] = v;
        }
      }
}

__global__ __launch_bounds__(256)
void gemm_mfma_k(const __hip_bfloat16* Apk, long lda,
                 const __hip_bfloat16* Bpk, long ldb,
                 const float* b1, const float* b2,
                 void* Cout, long ldc, int KS, int out_bf16)
{
    __shared__ __align__(16) char smem[20480];
    gemm_tile(Apk, lda, blockIdx.x*32, Bpk, ldb, blockIdx.y*128, b1, b2,
              Cout, ldc, KS, out_bf16, smem);
}

// ===========================================================================
// Gates GEMM (packed, gate-interleaved rows, tripled-K) + fused LSTM cell.
// Split-K2: each (m0,jb) tile has 2 blocks (half 0/1); last finisher does cell.
// ===========================================================================
__device__ void gates_cell_tile(const __hip_bfloat16* Apk, long lda,
                                const __hip_bfloat16* Wpk, long ldw,
                                const float* bpk, float* c_state, float* h_f32,
                                __hip_bfloat16* d1, int d1ld, int d1kp, int d1off,
                                __hip_bfloat16* d2, int d2ld, int d2kp, int d2off,
                                __hip_bfloat16* d3, int d3ld, int d3kp, int d3off,
                                int KS_all, int KS0, int half,
                                float* partial, int* cnt,
                                int m0, int jb, char* smem)
{
    char* sA = smem; char* sB = smem + 4096;
    floatx4 z4 = {0.f,0.f,0.f,0.f};
    floatx4 acc[2][2] = {{z4,z4},{z4,z4}};
    long kofs = half ? (long)KS0*32 : 0;
    int KS = half ? (KS_all - KS0) : KS0;
    mfma_loop_32x128(Apk + kofs, lda, m0, Wpk + (long)jb*128*ldw + kofs, ldw,
                     KS, sA, sB, acc);
    int tile = ((m0>>5)<<4) + jb;
    if (!splitk_handoff(acc, partial, cnt, tile, half)) return;
    __syncthreads();
    float (*gl)[36] = (float(*)[36])smem;   // 128x36 fp32, overlaps sA/sB
    const int tid = threadIdx.x, l = tid&63, w = tid>>6;
    for (int i = 0; i < 2; ++i)
      for (int jn = 0; jn < 2; ++jn) {
        int nl = (w*2+jn)*16 + (l&15);
        int mb = i*16 + ((l>>4)<<2);
        *(floatx4*)&gl[nl][mb] = acc[i][jn];
      }
    __syncthreads();
    for (int idx = tid; idx < 1024; idx += 256) {
        int u = idx >> 5, m = idx & 31;
        float g0 = gl[u   ][m] + bpk[jb*128 + u];
        float g1 = gl[32+u][m] + bpk[jb*128 + 32 + u];
        float g2 = gl[64+u][m] + bpk[jb*128 + 64 + u];
        float g3 = gl[96+u][m] + bpk[jb*128 + 96 + u];
        int bg = m0 + m, un = jb*32 + u;
        long ci = (long)bg*512 + un;
        float c2 = sigmoidf_(g1)*c_state[ci] + sigmoidf_(g0)*tanhf(g2);
        float h2 = sigmoidf_(g3)*tanhf(c2);
        c_state[ci] = c2;
        if (h_f32) h_f32[ci] = h2;
        store3(d1, (long)bg*d1ld, d1kp, d1off + un, h2);
        if (d2) store3(d2, (long)bg*d2ld, d2kp, d2off + un, h2);
        if (d3) store3(d3, (long)bg*d3ld, d3kp, d3off + un, h2);
    }
}

// ===========================================================================
// Alignment attention (per-batch block): fp32 logits, softmax, sent.
// ===========================================================================
__device__ void align_fn(int b, const float* dp, const float* langpre,
                         const float* hlang, const float* w2,
                         __hip_bfloat16* Ad_p, char* smem)
{
    float* dps    = (float*)smem;     // 512
    float* red    = dps + 512;        // 256
    float* logits = red + 256;        // 32
    float* smv    = logits + 32;      // 32
    float* ssum   = smv + 32;         // 1
    const int tid = threadIdx.x;
    for (int k = tid; k < 512; k += 256) dps[k] = dp[(long)b*512 + k];
    __syncthreads();
    {
        int ll = tid >> 3, part = tid & 7;
        const float* lp = langpre + ((long)b*32 + ll)*512 + part*64;
        const float* dpp = dps + part*64;
        const float* w2p = w2 + part*64;
        float acc = 0.f;
        for (int a = 0; a < 64; ++a)
            acc += tanhf(dpp[a] + lp[a]) * w2p[a];
        red[tid] = acc;
    }
    __syncthreads();
    if ((tid & 7) == 0) {
        float s = 0.f;
        for (int p2 = 0; p2 < 8; ++p2) s += red[tid + p2];
        logits[tid >> 3] = s;
    }
    __syncthreads();
    if (tid == 0) {
        float mx = logits[0];
        for (int i = 1; i < 32; ++i) mx = fmaxf(mx, logits[i]);
        float s = 0.f;
        for (int i = 0; i < 32; ++i) { float e = expf(logits[i]-mx); smv[i]=e; s+=e; }
        ssum[0] = s;
    }
    __syncthreads();
    {
        float acc = 0.f;
        const float* hl = hlang + (long)b*32*256 + tid;
        for (int i = 0; i < 32; ++i) acc += smv[i]*hl[(long)i*256];
        store3(Ad_p, (long)b*2688, 896, 104 + tid, acc/ssum[0]);
    }
}

// K_E: blocks 0-127 enc gates (split-K2); blocks 128-255 alignment
__global__ __launch_bounds__(256)
void enc_align_k(const __hip_bfloat16* Ae_p, const __hip_bfloat16* Wenc,
                 const float* benc, float* c_enc,
                 __hip_bfloat16* Ae_q, __hip_bfloat16* Ahe3,
                 const float* dp, const float* langpre, const float* hlang,
                 const float* w2, __hip_bfloat16* Ad_p,
                 float* partial, int* cnt)
{
    __shared__ __align__(16) char smem[20480];
    int bid = blockIdx.x;
    if (bid < 128) {
        int half = bid & 1, tl = bid >> 1;
        int m0 = ((tl>>4)&3)*32, jb = tl & 15;
        gates_cell_tile(Ae_p, 3552, Wenc, 3552, benc, c_enc, nullptr,
                        Ae_q, 3552, 1184, 664,  Ahe3, 1536, 512, 0,
                        nullptr, 0, 0, 0,
                        111, 56, half, partial, cnt, m0, jb, smem);
    } else {
        align_fn(bid-128, dp, langpre, hlang, w2, Ad_p, smem);
    }
}

// K_D: dec gates+cell (split-K2)
__global__ __launch_bounds__(256)
void dec_k(const __hip_bfloat16* Ad_p, const __hip_bfloat16* Wdec, const float* bdec,
           float* c_dec, float* h_dec,
           __hip_bfloat16* Ae_q, __hip_bfloat16* Ad_q, __hip_bfloat16* Ahd3,
           float* partial, int* cnt)
{
    __shared__ __align__(16) char smem[20480];
    int half = blockIdx.x & 1, tl = blockIdx.x >> 1;
    int m0 = ((tl>>4)&3)*32, jb = tl & 15;
    gates_cell_tile(Ad_p, 2688, Wdec, 2688, bdec, c_dec, h_dec,
                    Ae_q, 3552, 1184, 152,  Ad_q, 2688, 896, 360,
                    Ahd3, 1536, 512, 0,
                    84, 42, half, partial, cnt, m0, jb, smem);
}

// ===========================================================================
// K_M: mu/sigma/q. Wms3 packed interleaved; grid (4 m-tiles, 2 n-groups,
// 2 K-halves). Split-K2 with last-finisher epilogue.
// ===========================================================================
__global__ __launch_bounds__(256)
void musig_k(const __hip_bfloat16* Ahe3, const __hip_bfloat16* Wms3,
             const float* mu_b, const float* sig_b,
             const float* eps, __hip_bfloat16* Ad_p,
             float* partial, int* cnt)
{
    __shared__ __align__(16) char smem[20480];
    char* sA = smem; char* sB = smem + 4096;
    floatx4 z4 = {0.f,0.f,0.f,0.f};
    floatx4 acc[2][2] = {{z4,z4},{z4,z4}};
    int m0 = blockIdx.x*32, n0 = blockIdx.y*128, base = blockIdx.y*64;
    int half = blockIdx.z;
    long kofs = half ? 24L*32 : 0;
    mfma_loop_32x128(Ahe3 + kofs, 1536, m0, Wms3 + (long)n0*1536 + kofs, 1536,
                     24, sA, sB, acc);
    int tile = blockIdx.x*2 + blockIdx.y;
    if (!splitk_handoff(acc, partial, cnt, tile, half)) return;
    __syncthreads();
    float (*gl)[36] = (float(*)[36])smem;   // 128x36
    const int tid = threadIdx.x, l = tid&63, w = tid>>6;
    for (int i = 0; i < 2; ++i)
      for (int jn = 0; jn < 2; ++jn) {
        int nl = (w*2+jn)*16 + (l&15);
        int mb = i*16 + ((l>>4)<<2);
        *(floatx4*)&gl[nl][mb] = acc[i][jn];
      }
    __syncthreads();
    for (int idx = tid; idx < 2048; idx += 256) {
        int u = idx >> 5, m = idx & 31;
        int o = base + u;
        if (o >= 100) continue;
        int bg = m0 + m;
        float mu = gl[u][m] + mu_b[o];
        float sg = expf(gl[64+u][m] + sig_b[o]);
        float q = mu + eps[(long)bg*100 + o]*sg;
        store3(Ad_p, (long)bg*2688, 896, o, q);
    }
}

// ===========================================================================
// Fused 5-param attention head: one pass + wave shfl reduce (1 barrier).
// ===========================================================================
__device__ void attn_params5(const float* hd, const float* attn_W, const float* attn_b,
                             float* sP, float* scratch)
{
    const int tid = threadIdx.x;
    float p0=0.f,p1=0.f,p2=0.f,p3=0.f,p4=0.f;
    for (int k = tid; k < 512; k += 256) {
        float v = hd[k];
        p0 += v*attn_W[k];      p1 += v*attn_W[512+k];  p2 += v*attn_W[1024+k];
        p3 += v*attn_W[1536+k]; p4 += v*attn_W[2048+k];
    }
    for (int off = 32; off; off >>= 1) {
        p0 += __shfl_down(p0, off); p1 += __shfl_down(p1, off);
        p2 += __shfl_down(p2, off); p3 += __shfl_down(p3, off);
        p4 += __shfl_down(p4, off);
    }
    if ((tid & 63) == 0) {
        int wv = tid >> 6;
        scratch[wv*5+0]=p0; scratch[wv*5+1]=p1; scratch[wv*5+2]=p2;
        scratch[wv*5+3]=p3; scratch[wv*5+4]=p4;
    }
    __syncthreads();
    if (tid < 5) sP[tid] = scratch[tid]+scratch[5+tid]+scratch[10+tid]+scratch[15+tid]+attn_b[tid];
    __syncthreads();
}

// ===========================================================================
// Read-attention glimpse (per-batch block) -> r into Aenc (tripled) cols 0..149
// ===========================================================================
__device__ void glimpse_fn(int b, const float* x, const float* h_dec,
                           const float* attn_W, const float* attn_b,
                           __hip_bfloat16* Ae_q, char* smem)
{
    float* red = (float*)smem;   // 256 (scratch)
    float* sP  = red + 256;      // 8
    float* Fx  = sP + 8;         // 320
    float* Fy  = Fx + 320;       // 320
    float* denx= Fy + 320;       // 8
    float* deny= denx + 8;       // 8
    float* SFx = deny + 8;       // 8
    float* SFy = SFx + 8;        // 8
    float* tmp1= SFy + 8;        // 960
    const int tid = threadIdx.x;
    attn_params5(h_dec + (long)b*512, attn_W, attn_b, sP, red);
    float gx    = 32.5f*(sP[0]+1.f);
    float gy    = 32.5f*(sP[1]+1.f);
    float s2    = expf(sP[2]);
    float delta = 15.75f*expf(sP[3]);
    for (int p = tid; p < 320; p += 256) {
        int i = p >> 6, a = p & 63;
        float mux = gx + ((float)i - 3.0f)*delta;
        float muy = gy + ((float)i - 3.0f)*delta;
        float dx = (float)a - mux, dy = (float)a - muy;
        Fx[i*64+a] = expf(-dx*dx/(2.f*s2));
        Fy[i*64+a] = expf(-dy*dy/(2.f*s2));
    }
    __syncthreads();
    if (tid < 10) {
        int i = tid % 5;
        const float* F = (tid < 5) ? (Fx + i*64) : (Fy + i*64);
        float s = 0.f;
        for (int a = 0; a < 64; ++a) s += F[a];
        if (tid < 5) denx[i] = s + 1e-8f; else deny[i] = s + 1e-8f;
    }
    __syncthreads();
    for (int p = tid; p < 320; p += 256) {
        int i = p >> 6, a = p & 63;
        Fx[i*64+a] /= denx[i];
        Fy[i*64+a] /= deny[i];
    }
    __syncthreads();
    if (tid < 10) {
        int i = tid % 5;
        const float* F = (tid < 5) ? (Fx + i*64) : (Fy + i*64);
        float s = 0.f;
        for (int a = 0; a < 64; ++a) s += F[a];
        if (tid < 5) SFx[i] = s; else SFy[i] = s;
    }
    __syncthreads();
    for (int p = tid; p < 192; p += 256) {
        int cc = p / 64, yy = p - cc*64;
        const float4* row4 = (const float4*)(x + (long)b*12288 + cc*4096 + yy*64);
        float a0=0,a1=0,a2=0,a3=0,a4=0;
        #pragma unroll
        for (int q4 = 0; q4 < 16; ++q4) {
            float4 v = row4[q4];
            int xx = q4*4;
            a0 += v.x*Fx[xx]     + v.y*Fx[xx+1]     + v.z*Fx[xx+2]     + v.w*Fx[xx+3];
            a1 += v.x*Fx[64+xx]  + v.y*Fx[64+xx+1]  + v.z*Fx[64+xx+2]  + v.w*Fx[64+xx+3];
            a2 += v.x*Fx[128+xx] + v.y*Fx[128+xx+1] + v.z*Fx[128+xx+2] + v.w*Fx[128+xx+3];
            a3 += v.x*Fx[192+xx] + v.y*Fx[192+xx+1] + v.z*Fx[192+xx+2] + v.w*Fx[192+xx+3];
            a4 += v.x*Fx[256+xx] + v.y*Fx[256+xx+1] + v.z*Fx[256+xx+2] + v.w*Fx[256+xx+3];
        }
        tmp1[(cc*64+yy)*5+0]=a0; tmp1[(cc*64+yy)*5+1]=a1; tmp1[(cc*64+yy)*5+2]=a2;
        tmp1[(cc*64+yy)*5+3]=a3; tmp1[(cc*64+yy)*5+4]=a4;
    }
    __syncthreads();
    if (tid < 75) {
        int cc = tid/25, i = (tid/5)%5, j = tid%5;
        float g = 0.f;
        for (int yy = 0; yy < 64; ++yy) g += Fy[i*64+yy]*tmp1[(cc*64+yy)*5 + j];
        float gamma = expf(sP[4]);
        long ro = (long)b*3552;
        store3(Ae_q, ro, 1184, tid,      gamma*g);
        store3(Ae_q, ro, 1184, 75 + tid, gamma*(g - 0.5f*SFy[i]*SFx[j]));
    }
}

// ===========================================================================
// Write head (per-batch block), fp32 throughout
// ===========================================================================
__device__ void write_fn(int b, const float* h_dec,
                         const float* write_W, const float* write_b,
                         const float* attn_W, const float* attn_b,
                         float* outp, char* smem)
{
    float* hs  = (float*)smem;    // 512
    float* red = hs + 512;        // 256 (scratch)
    float* sP  = red + 256;       // 8
    float* w75 = sP + 8;          // 80
    float* Fx  = w75 + 80;        // 320
    float* Fy  = Fx + 320;        // 320
    float* denx= Fy + 320;        // 8
    float* deny= denx + 8;        // 8
    float* t2  = deny + 8;        // 960
    const int tid = threadIdx.x;
    for (int k = tid; k < 512; k += 256) hs[k] = h_dec[(long)b*512 + k];
    __syncthreads();
    attn_params5(hs, attn_W, attn_b, sP, red);
    float gx    = 32.5f*(sP[0]+1.f);
    float gy    = 32.5f*(sP[1]+1.f);
    float s2    = expf(sP[2]);
    float delta = 15.75f*expf(sP[3]);
    float inv_g = 1.f/expf(sP[4]);
    if (tid < 75) {
        const float4* w4 = (const float4*)(write_W + (long)tid*512);
        const float4* h4 = (const float4*)hs;
        float acc = 0.f;
        for (int k = 0; k < 128; ++k) {
            float4 wv = w4[k], hv = h4[k];
            acc += wv.x*hv.x + wv.y*hv.y + wv.z*hv.z + wv.w*hv.w;
        }
        w75[tid] = acc + write_b[tid];
    }
    for (int p = tid; p < 320; p += 256) {
        int i = p >> 6, a = p & 63;
        float mux = gx + ((float)i - 3.0f)*delta;
        float muy = gy + ((float)i - 3.0f)*delta;
        float dx = (float)a - mux, dy = (float)a - muy;
        Fx[i*64+a] = expf(-dx*dx/(2.f*s2));
        Fy[i*64+a] = expf(-dy*dy/(2.f*s2));
    }
    __syncthreads();
    if (tid < 10) {
        int i = tid % 5;
        const float* F = (tid < 5) ? (Fx + i*64) : (Fy + i*64);
        float s = 0.f;
        for (int a = 0; a < 64; ++a) s += F[a];
        if (tid < 5) denx[i] = s + 1e-8f; else deny[i] = s + 1e-8f;
    }
    __syncthreads();
    for (int p = tid; p < 320; p += 256) {
        int i = p >> 6, a = p & 63;
        Fx[i*64+a] /= denx[i];
        Fy[i*64+a] /= deny[i];
    }
    __syncthreads();
    for (int p = tid; p < 960; p += 256) {
        int cc = p / 320, rem = p - cc*320;
        int i = rem / 64, xx = rem - i*64;
        float acc = 0.f;
        for (int j = 0; j < 5; ++j) acc += w75[cc*25 + i*5 + j]*Fx[j*64+xx];
        t2[(cc*5+i)*64+xx] = acc;
    }
    __syncthreads();
    float* ob = outp + (long)b*12288;
    for (int p = tid; p < 12288; p += 256) {
        int cc = p >> 12, yy = (p >> 6) & 63, xx = p & 63;
        float acc = 0.f;
        for (int i = 0; i < 5; ++i) acc += Fy[i*64+yy]*t2[(cc*5+i)*64+xx];
        ob[p] = acc*inv_g;
    }
}

// K_G: blocks 0-127 glimpse(t+1); 128-143 dp GEMM(t+1); 144-271 write(t)
__global__ __launch_bounds__(256)
void wgd_k(const float* x, const float* h_dec,
           const float* attn_W, const float* attn_b,
           const float* write_W, const float* write_b,
           float* outp,
           __hip_bfloat16* Ae_q,
           const __hip_bfloat16* Ahd3, const __hip_bfloat16* W1dec3,
           float* dp)
{
    __shared__ __align__(16) char smem[20480];
    int bid = blockIdx.x;
    if (bid < 128) {
        glimpse_fn(bid, x, h_dec, attn_W, attn_b, Ae_q, smem);
    } else if (bid < 144) {
        int t = bid - 128;
        gemm_tile(Ahd3, 1536, (t&3)*32, W1dec3, 1536, (t>>2)*128,
                  nullptr, nullptr, dp, 512, 48, 0, smem);
    } else {
        if (outp) write_fn(bid-144, h_dec, write_W, write_b, attn_W, attn_b, outp, smem);
    }
}

// ===========================================================================
// Language bi-LSTM: fused over all 32 steps. One block = 2 batches x 1 dir,
// 512 threads; thread = one gate row, Whh row cached in 32 float4 REGISTERS.
// ===========================================================================
__global__ __launch_bounds__(512)
void lang_all_k(const float* xpf, const float* xpb,
                const float* Whh_f, const float* Whh_b,
                float* hlang)
{
    const int pr  = blockIdx.x & 63;      // batch pair
    const int dir = blockIdx.x >> 6;
    const int tid = threadIdx.x;          // gate row 0..511
    const int b0  = pr*2;
    const float* Whh = dir ? Whh_b : Whh_f;
    const float* xps = dir ? xpb : xpf;
    __shared__ __align__(16) float hs[2][128];
    __shared__ float gs[2][512];
    float4 wr[32];
    {
        const float4* w4 = (const float4*)(Whh + (long)tid*128);
        #pragma unroll
        for (int k = 0; k < 32; ++k) wr[k] = w4[k];
    }
    if (tid < 256) hs[tid>>7][tid&127] = 0.f;
    float cst = 0.f;
    __syncthreads();
    for (int s = 0; s < 32; ++s) {
        const int l = dir ? (31 - s) : s;
        const float4* h40 = (const float4*)hs[0];
        const float4* h41 = (const float4*)hs[1];
        float a0 = 0.f, a1 = 0.f;
        #pragma unroll
        for (int k = 0; k < 32; ++k) {
            float4 wv = wr[k], h0 = h40[k], h1 = h41[k];
            a0 += wv.x*h0.x + wv.y*h0.y + wv.z*h0.z + wv.w*h0.w;
            a1 += wv.x*h1.x + wv.y*h1.y + wv.z*h1.z + wv.w*h1.w;
        }
        gs[0][tid] = a0 + xps[((long)b0*32 + l)*512 + tid];
        gs[1][tid] = a1 + xps[((long)(b0+1)*32 + l)*512 + tid];
        __syncthreads();   // gs ready; all hs reads of this step done
        if (tid < 256) {
            int bb = tid >> 7, u = tid & 127;
            float c2 = sigmoidf_(gs[bb][128+u])*cst + sigmoidf_(gs[bb][u])*tanhf(gs[bb][256+u]);
            float h2 = sigmoidf_(gs[bb][384+u])*tanhf(c2);
            cst = c2;
            hlang[((long)(b0+bb)*32 + l)*256 + dir*128 + u] = h2;
            hs[bb][u] = h2;
        }
        __syncthreads();   // hs(s+1) ready
    }
}

// ===========================================================================
// Packing kernels: fp32 -> tripled split-bf16. 2D grid (y = row) — no
// per-element integer division.
// ===========================================================================
__global__ void pack_a3_k(__hip_bfloat16* dst, int KP,
                          const float* src, int ld, int K1)
{
    int k3 = blockIdx.x*256 + threadIdx.x;
    int K3 = 3*KP;
    if (k3 >= K3) return;
    long n = blockIdx.y;
    int plane = (k3 >= KP) + (k3 >= 2*KP);
    int k = k3 - plane*KP;
    float v = (k < K1) ? src[n*ld + k] : 0.f;
    __hip_bfloat16 hi = __float2bfloat16(v);
    float lo = v - __bfloat162float(hi);
    dst[n*K3 + k3] = (plane==1) ? __float2bfloat16(lo) : hi;
}

__global__ void pack_w3_k(__hip_bfloat16* dst, int KP,
                          const float* src, int ld, int K1)
{
    int k3 = blockIdx.x*256 + threadIdx.x;
    int K3 = 3*KP;
    if (k3 >= K3) return;
    long n = blockIdx.y;
    int plane = (k3 >= KP) + (k3 >= 2*KP);
    int k = k3 - plane*KP;
    float v = (k < K1) ? src[n*ld + k] : 0.f;
    __hip_bfloat16 hi = __float2bfloat16(v);
    float lo = v - __bfloat162float(hi);
    dst[n*K3 + k3] = (plane==2) ? __float2bfloat16(lo) : hi;
}

__global__ void pack_gates3_k(__hip_bfloat16* dst, int KP,
                              const float* Wih, int ldih, int K1, int off2, int K2, int off3,
                              const float* Whh)
{
    int k3 = blockIdx.x*256 + threadIdx.x;
    int K3 = 3*KP;
    if (k3 >= K3) return;
    int p = blockIdx.y;
    int plane = (k3 >= KP) + (k3 >= 2*KP);
    int k = k3 - plane*KP;
    int j = p >> 7, g = (p>>5)&3, uu = p&31;
    int n = g*512 + j*32 + uu;
    float v = 0.f;
    if (k < K1)                          v = Wih[(long)n*ldih + k];
    else if (k >= off2 && k < off2+K2)   v = Wih[(long)n*ldih + K1 + (k-off2)];
    else if (k >= off3 && k < off3+512)  v = Whh[(long)n*512 + (k-off3)];
    __hip_bfloat16 hi = __float2bfloat16(v);
    float lo = v - __bfloat162float(hi);
    dst[(long)p*K3 + k3] = (plane==2) ? __float2bfloat16(lo) : hi;
}

__global__ void pack_gbias_k(float* dst, const float* bih, const float* bhh)
{
    int p = blockIdx.x*256 + threadIdx.x;
    if (p >= 2048) return;
    int j = p >> 7, g = (p>>5)&3, uu = p&31;
    int n = g*512 + j*32 + uu;
    dst[p] = bih[n] + bhh[n];
}

// Interleaved mu/sig pack: row p: group g=p>>7, u=p&127;
//   u<64 -> mu[g*64+u], u>=64 -> sig[g*64+(u-64)]; pad when index >= 100.
__global__ void pack_musig3_k(__hip_bfloat16* dst, const float* mu_W, const float* sig_W)
{
    int k3 = blockIdx.x*256 + threadIdx.x;
    if (k3 >= 1536) return;
    int p = blockIdx.y;
    int plane = k3 >> 9, k = k3 & 511;
    int u = p & 127, base = (p >> 7)*64;
    int z = base + (u & 63);
    const float* W = (u < 64) ? mu_W : sig_W;
    float v = (z < 100) ? W[(long)z*512 + k] : 0.f;
    __hip_bfloat16 hi = __float2bfloat16(v);
    float lo = v - __bfloat162float(hi);
    dst[(long)p*1536 + k3] = (plane==2) ? __float2bfloat16(lo) : hi;
}

// ===========================================================================
extern "C" void kernel_launch(void* const* d_in, const int* in_sizes, int n_in,
                              void* d_out, int out_size, void* d_ws, size_t ws_size,
                              hipStream_t stream)
{
    const float* x        = (const float*)d_in[0];
    const float* y        = (const float*)d_in[1];
    const float* eps_q    = (const float*)d_in[2];
    const float* enc_Wih  = (const float*)d_in[3];
    const float* enc_Whh  = (const float*)d_in[4];
    const float* enc_bih  = (const float*)d_in[5];
    const float* enc_bhh  = (const float*)d_in[6];
    const float* dec_Wih  = (const float*)d_in[7];
    const float* dec_Whh  = (const float*)d_in[8];
    const float* dec_bih  = (const float*)d_in[9];
    const float* dec_bhh  = (const float*)d_in[10];
    const float* mu_W     = (const float*)d_in[11];
    const float* mu_b     = (const float*)d_in[12];
    const float* sig_W    = (const float*)d_in[13];
    const float* sig_b    = (const float*)d_in[14];
    const float* write_W  = (const float*)d_in[15];
    const float* write_b  = (const float*)d_in[16];
    const float* align_W1 = (const float*)d_in[17];
    const float* align_b1 = (const float*)d_in[18];
    const float* align_w2 = (const float*)d_in[19];
    const float* attn_W   = (const float*)d_in[20];
    const float* attn_b   = (const float*)d_in[21];
    const float* lf_Wih   = (const float*)d_in[22];
    const float* lf_Whh   = (const float*)d_in[23];
    const float* lf_bih   = (const float*)d_in[24];
    const float* lf_bhh   = (const float*)d_in[25];
    const float* lb_Wih   = (const float*)d_in[26];
    const float* lb_Whh   = (const float*)d_in[27];
    const float* lb_bih   = (const float*)d_in[28];
    const float* lb_bhh   = (const float*)d_in[29];
    float* out = (float*)d_out;

    float* ws = (float*)d_ws;
    size_t off = 0;
    auto alloc = [&](size_t n){ float* p = ws + off; off += n; return p; };

    // ---- zeroed region ----
    float* Aenc0f = alloc(227328);   // 128x3552 bf16
    float* Aenc1f = alloc(227328);
    float* Adec0f = alloc(172032);   // 128x2688 bf16
    float* Adec1f = alloc(172032);
    float* Ahd3f  = alloc(98304);    // 128x1536 bf16 (h_dec split, for dp GEMM)
    float* Ahe3f  = alloc(98304);    // 128x1536 bf16 (h_enc split, for musig)
    float* c_enc  = alloc(65536);
    float* c_dec  = alloc(65536);
    float* h_dec  = alloc(65536);
    int*   enc_cnt = (int*)alloc(2048);   // 32 steps x 64 tiles
    int*   dec_cnt = (int*)alloc(2048);
    int*   ms_cnt  = (int*)alloc(256);    // 32 steps x 8 tiles
    size_t zero_floats = off;
    // ---- persistent ----
    float* dpb      = alloc(65536);     // 128x512 fp32
    float* hlangf   = alloc(1048576);   // 4096x256 fp32
    float* hlang3f  = alloc(1572864);   // 4096x768 bf16 tripled
    float* langpre  = alloc(2097152);   // 4096x512 fp32
    float* W1lang3f = alloc(196608);    // 512x768 bf16
    float* W1dec3f  = alloc(393216);    // 512x1536 bf16
    float* enc_part = alloc(524288);    // 64 tiles x 2 halves x 4096 fp32
    float* dec_part = alloc(524288);
    float* ms_part  = alloc(65536);     // 8 tiles x 2 x 4096
    // ---- shared region (phase1 / phase2 overlap) ----
    float* shared = alloc(6651904);
    // phase1 layout
    float* y3f   = shared;               // 4096x960 bf16  = 1966080 f
    float* Wlf3f = shared + 1966080;     // 512x960 bf16   = 245760 f
    float* Wlb3f = Wlf3f + 245760;
    float* xpf   = Wlb3f + 245760;       // 4096x512 fp32  = 2097152 f
    float* xpb   = xpf + 2097152;
    // phase2 layout (same region, used after lang steps)
    float* Wenc3f = shared;              // 2048x3552 bf16 = 3637248 f
    float* Wdec3f = Wenc3f + 3637248;    // 2048x2688 bf16 = 2752512 f
    float* Wms3f  = Wdec3f + 2752512;    // 256x1536 bf16  = 196608 f
    float* benc   = Wms3f + 196608;      // 2048 f
    float* bdec   = benc + 2048;         // 2048 f

    __hip_bfloat16* Aenc0 = (__hip_bfloat16*)Aenc0f;
    __hip_bfloat16* Aenc1 = (__hip_bfloat16*)Aenc1f;
    __hip_bfloat16* Adec0 = (__hip_bfloat16*)Adec0f;
    __hip_bfloat16* Adec1 = (__hip_bfloat16*)Adec1f;
    __hip_bfloat16* Ahd3  = (__hip_bfloat16*)Ahd3f;
    __hip_bfloat16* Ahe3  = (__hip_bfloat16*)Ahe3f;
    __hip_bfloat16* hlang3= (__hip_bfloat16*)hlang3f;
    __hip_bfloat16* W1lang3=(__hip_bfloat16*)W1lang3f;
    __hip_bfloat16* W1dec3= (__hip_bfloat16*)W1dec3f;
    __hip_bfloat16* y3    = (__hip_bfloat16*)y3f;
    __hip_bfloat16* Wlf3  = (__hip_bfloat16*)Wlf3f;
    __hip_bfloat16* Wlb3  = (__hip_bfloat16*)Wlb3f;
    __hip_bfloat16* Wenc3 = (__hip_bfloat16*)Wenc3f;
    __hip_bfloat16* Wdec3 = (__hip_bfloat16*)Wdec3f;
    __hip_bfloat16* Wms3  = (__hip_bfloat16*)Wms3f;

    hipMemsetAsync(ws, 0, zero_floats*sizeof(float), stream);

    // ---- phase 1: language bi-LSTM (fp32 recurrence, split-bf16 GEMMs) ----
    pack_a3_k<<<dim3(4,4096),256,0,stream>>>(y3, 320, y, 300, 300);
    pack_w3_k<<<dim3(4,512),256,0,stream>>>(Wlf3, 320, lf_Wih, 300, 300);
    pack_w3_k<<<dim3(4,512),256,0,stream>>>(Wlb3, 320, lb_Wih, 300, 300);
    pack_w3_k<<<dim3(3,512),256,0,stream>>>(W1lang3, 256, align_W1+512, 768, 256);
    pack_w3_k<<<dim3(6,512),256,0,stream>>>(W1dec3, 512, align_W1, 768, 512);
    gemm_mfma_k<<<dim3(128,4),256,0,stream>>>(y3, 960, Wlf3, 960, lf_bih, lf_bhh, xpf, 512, 30, 0);
    gemm_mfma_k<<<dim3(128,4),256,0,stream>>>(y3, 960, Wlb3, 960, lb_bih, lb_bhh, xpb, 512, 30, 0);
    lang_all_k<<<128,512,0,stream>>>(xpf, xpb, lf_Whh, lb_Whh, hlangf);
    pack_a3_k<<<dim3(3,4096),256,0,stream>>>(hlang3, 256, hlangf, 256, 256);
    gemm_mfma_k<<<dim3(128,4),256,0,stream>>>(hlang3, 768, W1lang3, 768, align_b1, nullptr, langpre, 512, 24, 0);

    // ---- phase 2 weight packs (shared region reuse: phase1 buffers dead) ----
    pack_gates3_k<<<dim3(42,2048),256,0,stream>>>(Wenc3, 1184, enc_Wih, 662, 150, 152, 512, 664, enc_Whh);
    pack_gates3_k<<<dim3(32,2048),256,0,stream>>>(Wdec3, 896, dec_Wih, 356, 100, 104, 256, 360, dec_Whh);
    pack_gbias_k<<<8,256,0,stream>>>(benc, enc_bih, enc_bhh);
    pack_gbias_k<<<8,256,0,stream>>>(bdec, dec_bih, dec_bhh);
    pack_musig3_k<<<dim3(6,256),256,0,stream>>>(Wms3, mu_W, sig_W);

    // ---- priming: glimpse + dp for t=0 (h_dec = 0, Ahd3 = 0 -> dp = 0) ----
    wgd_k<<<272,256,0,stream>>>(x, h_dec, attn_W, attn_b, write_W, write_b,
                                nullptr, Aenc0, Ahd3, W1dec3, dpb);

    for (int t = 0; t < 32; ++t) {
        int p = t & 1;
        __hip_bfloat16* Ae_p = p ? Aenc1 : Aenc0;
        __hip_bfloat16* Ae_q = p ? Aenc0 : Aenc1;
        __hip_bfloat16* Ad_p = p ? Adec1 : Adec0;
        __hip_bfloat16* Ad_q = p ? Adec0 : Adec1;
        enc_align_k<<<256,256,0,stream>>>(Ae_p, Wenc3, benc, c_enc, Ae_q, Ahe3,
                                          dpb, langpre, hlangf, align_w2, Ad_p,
                                          enc_part, enc_cnt + t*64);
        musig_k<<<dim3(4,2,2),256,0,stream>>>(Ahe3, Wms3, mu_b, sig_b,
                                              eps_q + (long)t*12800, Ad_p,
                                              ms_part, ms_cnt + t*8);
        dec_k<<<128,256,0,stream>>>(Ad_p, Wdec3, bdec, c_dec, h_dec, Ae_q, Ad_q, Ahd3,
                                    dec_part, dec_cnt + t*64);
        wgd_k<<<272,256,0,stream>>>(x, h_dec, attn_W, attn_b, write_W, write_b,
                                    out + (long)t*128*12288, Ae_q, Ahd3, W1dec3, dpb);
    }
}

// Round 5
// 3581.483 us; speedup vs baseline: 1.3049x; 1.3049x over previous
//
#include <hip/hip_runtime.h>
#include <hip/hip_bf16.h>
#include <math.h>

typedef __attribute__((ext_vector_type(8))) short short8;
typedef __attribute__((ext_vector_type(4))) float floatx4;

__device__ __forceinline__ float sigmoidf_(float v){ return 1.f/(1.f+expf(-v)); }

__device__ __forceinline__ floatx4 mfma16(short8 a, short8 b, floatx4 c) {
    return __builtin_amdgcn_mfma_f32_16x16x32_bf16(a, b, c, 0, 0, 0);
}

// split-bf16 store: v -> [hi | lo | hi] planes of a tripled-K activation row
__device__ __forceinline__ void store3(__hip_bfloat16* p, long row, int kp, int col, float v){
    __hip_bfloat16 hi = __float2bfloat16(v);
    float lo = v - __bfloat162float(hi);
    p[row + col]        = hi;
    p[row + kp + col]   = __float2bfloat16(lo);
    p[row + 2*kp + col] = hi;
}

// ===========================================================================
// MFMA mainloop: C-tile 32m x 128n, 256 lanes (4 waves), tid passed in.
// K processed in 64-elem iters (2 x 32-K substeps per barrier pair), register
// prefetch depth = 2 iters. sA = 4KB, sB = 16KB.
// Barrier count: nb(KS) = KS + (KS&1)  (loop 2*NIT, K-tail +2).
// ===========================================================================
#define MFMA_TILE_BODY \
    { const short8* A8 = (const short8*)sA; \
      const short8* B8 = (const short8*)sB; \
      short8 a0 = A8[l], a1 = A8[64+l]; \
      short8 b0 = B8[(w*2)*64 + l], b1 = B8[(w*2+1)*64 + l]; \
      acc[0][0] = mfma16(a0,b0,acc[0][0]); \
      acc[0][1] = mfma16(a0,b1,acc[0][1]); \
      acc[1][0] = mfma16(a1,b0,acc[1][0]); \
      acc[1][1] = mfma16(a1,b1,acc[1][1]); }

#define MFMA_TILE_BODY2 \
    { const short8* A8 = (const short8*)sA; \
      const short8* B8 = (const short8*)sB; \
      short8 a0 = A8[l], a1 = A8[64+l]; \
      short8 b0 = B8[(w*2)*64 + l], b1 = B8[(w*2+1)*64 + l]; \
      acc[0][0] = mfma16(a0,b0,acc[0][0]); \
      acc[0][1] = mfma16(a0,b1,acc[0][1]); \
      acc[1][0] = mfma16(a1,b0,acc[1][0]); \
      acc[1][1] = mfma16(a1,b1,acc[1][1]); \
      short8 c0 = A8[128+l], c1 = A8[192+l]; \
      short8 d0 = B8[512+(w*2)*64 + l], d1 = B8[512+(w*2+1)*64 + l]; \
      acc[0][0] = mfma16(c0,d0,acc[0][0]); \
      acc[0][1] = mfma16(c0,d1,acc[0][1]); \
      acc[1][0] = mfma16(c1,d0,acc[1][0]); \
      acc[1][1] = mfma16(c1,d1,acc[1][1]); }

__device__ void mfma_loop_32x128_t(int tid,
                                   const __hip_bfloat16* Apk, long lda, int m0,
                                   const __hip_bfloat16* Wrows, long ldb,
                                   int KS, char* sA, char* sB, floatx4 acc[2][2])
{
    const int l = tid & 63, w = tid >> 6;
    const char* Ab = (const char*)(Apk + (long)(m0 + (tid>>6)*16 + (tid&15))*lda
                                   + (long)(((tid&63)>>4)*8));
    int r0 = tid >> 2, qd = tid & 3;
    const char* Bb0 = (const char*)(Wrows + (long)r0*ldb + qd*8);
    const char* Bb1 = (const char*)(Wrows + (long)(r0+64)*ldb + qd*8);
    int4* sAv = (int4*)sA;
    int4* sBv = (int4*)sB;
    int bs0 = (r0>>4)*64 + (r0&15) + (qd<<4);
    int bs1 = bs0 + 256;
    const int NIT = KS >> 1, tail = KS & 1;
    int4 aE0,aE1,b0E0,b0E1,b1E0,b1E1;
    int4 aO0,aO1,b0O0,b0O1,b1O0,b1O1;
    if (NIT > 0) {
        if (tid < 128) { aE0 = *(const int4*)Ab; aE1 = *(const int4*)(Ab+64); }
        b0E0 = *(const int4*)Bb0; b0E1 = *(const int4*)(Bb0+64);
        b1E0 = *(const int4*)Bb1; b1E1 = *(const int4*)(Bb1+64);
    }
    if (NIT > 1) {
        if (tid < 128) { aO0 = *(const int4*)(Ab+128); aO1 = *(const int4*)(Ab+192); }
        b0O0 = *(const int4*)(Bb0+128); b0O1 = *(const int4*)(Bb0+192);
        b1O0 = *(const int4*)(Bb1+128); b1O1 = *(const int4*)(Bb1+192);
    }
    int it = 0;
    for (; it + 1 < NIT; it += 2) {
        // even buffer
        __syncthreads();
        if (tid < 128) { sAv[tid] = aE0; sAv[128+tid] = aE1; }
        sBv[bs0] = b0E0; sBv[bs1] = b1E0; sBv[512+bs0] = b0E1; sBv[512+bs1] = b1E1;
        __syncthreads();
        if (it + 2 < NIT) {
            long off = (long)(it+2)*128;
            if (tid < 128) { aE0 = *(const int4*)(Ab+off); aE1 = *(const int4*)(Ab+off+64); }
            b0E0 = *(const int4*)(Bb0+off); b0E1 = *(const int4*)(Bb0+off+64);
            b1E0 = *(const int4*)(Bb1+off); b1E1 = *(const int4*)(Bb1+off+64);
        }
        MFMA_TILE_BODY2
        // odd buffer
        __syncthreads();
        if (tid < 128) { sAv[tid] = aO0; sAv[128+tid] = aO1; }
        sBv[bs0] = b0O0; sBv[bs1] = b1O0; sBv[512+bs0] = b0O1; sBv[512+bs1] = b1O1;
        __syncthreads();
        if (it + 3 < NIT) {
            long off = (long)(it+3)*128;
            if (tid < 128) { aO0 = *(const int4*)(Ab+off); aO1 = *(const int4*)(Ab+off+64); }
            b0O0 = *(const int4*)(Bb0+off); b0O1 = *(const int4*)(Bb0+off+64);
            b1O0 = *(const int4*)(Bb1+off); b1O1 = *(const int4*)(Bb1+off+64);
        }
        MFMA_TILE_BODY2
    }
    if (it < NIT) {   // NIT odd: final 64-K iter from even buffer
        __syncthreads();
        if (tid < 128) { sAv[tid] = aE0; sAv[128+tid] = aE1; }
        sBv[bs0] = b0E0; sBv[bs1] = b1E0; sBv[512+bs0] = b0E1; sBv[512+bs1] = b1E1;
        __syncthreads();
        MFMA_TILE_BODY2
    }
    if (tail) {       // final 32-K step
        long off = (long)NIT*128;
        int4 aT, bT0, bT1;
        if (tid < 128) aT = *(const int4*)(Ab+off);
        bT0 = *(const int4*)(Bb0+off); bT1 = *(const int4*)(Bb1+off);
        __syncthreads();
        if (tid < 128) sAv[tid] = aT;
        sBv[bs0] = bT0; sBv[bs1] = bT1;
        __syncthreads();
        MFMA_TILE_BODY
    }
}

__device__ void mfma_loop_32x128(const __hip_bfloat16* Apk, long lda, int m0,
                                 const __hip_bfloat16* Wrows, long ldb,
                                 int KS, char* sA, char* sB, floatx4 acc[2][2])
{
    mfma_loop_32x128_t(threadIdx.x, Apk, lda, m0, Wrows, ldb, KS, sA, sB, acc);
}

// ===========================================================================
// Split-K2 INSIDE one 512-thread block: waves 0-3 do K[0..KS0), waves 4-7 do
// K[KS0..KS_all). LDS combine (no fence/atomic/global round-trip).
// nb(KS)=KS+(KS&1); with KS0 chosen so both halves emit equal barrier counts
// (56/56 enc, 42/42 dec, 24/24 musig+dp).
// smem: [0,20480) kg0 sA+sB; [20480,40960) kg1; [40960,57344) combine.
// On return kg0 threads (tid<256) hold the combined acc.
// ===========================================================================
__device__ void mfma_splitk2(const __hip_bfloat16* Apk, long lda, int m0,
                             const __hip_bfloat16* Wrows, long ldb,
                             int KS_all, int KS0, char* smem, floatx4 acc[2][2])
{
    const int tid = threadIdx.x;
    const int kg = tid >> 8, t2 = tid & 255;
    char* sA = smem + kg*20480;
    char* sB = sA + 4096;
    int KS = kg ? (KS_all - KS0) : KS0;
    long kofs = kg ? (long)KS0*32 : 0;
    mfma_loop_32x128_t(t2, Apk + kofs, lda, m0, Wrows + kofs, ldb, KS, sA, sB, acc);
    float* comb = (float*)(smem + 40960);
    __syncthreads();
    if (kg) {
        float* pb = comb + t2*16;
        *(floatx4*)(pb)    = acc[0][0];
        *(floatx4*)(pb+4)  = acc[0][1];
        *(floatx4*)(pb+8)  = acc[1][0];
        *(floatx4*)(pb+12) = acc[1][1];
    }
    __syncthreads();
    if (!kg) {
        const float* pb = comb + t2*16;
        acc[0][0] += *(const floatx4*)(pb);
        acc[0][1] += *(const floatx4*)(pb+4);
        acc[1][0] += *(const floatx4*)(pb+8);
        acc[1][1] += *(const floatx4*)(pb+12);
    }
}

// Generic 32x128 tile (256 threads): D = A@W^T + b1 + b2 -> fp32 or bf16 out
__device__ void gemm_tile(const __hip_bfloat16* Apk, long lda, int m0,
                          const __hip_bfloat16* Wpk, long ldb, int n0,
                          const float* b1, const float* b2,
                          void* Cout, long ldc, int KS, int out_bf16, char* smem)
{
    char* sA = smem; char* sB = smem + 4096;
    floatx4 z4 = {0.f,0.f,0.f,0.f};
    floatx4 acc[2][2] = {{z4,z4},{z4,z4}};
    mfma_loop_32x128(Apk, lda, m0, Wpk + (long)n0*ldb, ldb, KS, sA, sB, acc);
    const int tid = threadIdx.x, l = tid&63, w = tid>>6;
    for (int i = 0; i < 2; ++i)
      for (int jn = 0; jn < 2; ++jn) {
        int n = n0 + (w*2+jn)*16 + (l&15);
        float bb = (b1? b1[n]:0.f) + (b2? b2[n]:0.f);
        for (int r = 0; r < 4; ++r) {
            int m = m0 + i*16 + ((l>>4)<<2) + r;
            float v = acc[i][jn][r] + bb;
            if (out_bf16) ((__hip_bfloat16*)Cout)[(long)m*ldc + n] = __float2bfloat16(v);
            else          ((float*)Cout)[(long)m*ldc + n] = v;
        }
      }
}

// 512-thread split-K2 variant, fp32 out, no bias (for dp GEMM)
__device__ void gemm_tile_sk2(const __hip_bfloat16* Apk, long lda, int m0,
                              const __hip_bfloat16* Wpk, long ldb, int n0,
                              float* Cout, long ldc, int KS_all, int KS0, char* smem)
{
    floatx4 z4 = {0.f,0.f,0.f,0.f};
    floatx4 acc[2][2] = {{z4,z4},{z4,z4}};
    mfma_splitk2(Apk, lda, m0, Wpk + (long)n0*ldb, ldb, KS_all, KS0, smem, acc);
    const int tid = threadIdx.x;
    if (tid >= 256) return;   // no further barriers
    const int l = tid&63, w = tid>>6;
    for (int i = 0; i < 2; ++i)
      for (int jn = 0; jn < 2; ++jn) {
        int n = n0 + (w*2+jn)*16 + (l&15);
        for (int r = 0; r < 4; ++r) {
            int m = m0 + i*16 + ((l>>4)<<2) + r;
            Cout[(long)m*ldc + n] = acc[i][jn][r];
        }
      }
}

__global__ __launch_bounds__(256)
void gemm_mfma_k(const __hip_bfloat16* Apk, long lda,
                 const __hip_bfloat16* Bpk, long ldb,
                 const float* b1, const float* b2,
                 void* Cout, long ldc, int KS, int out_bf16)
{
    __shared__ __align__(16) char smem[20480];
    gemm_tile(Apk, lda, blockIdx.x*32, Bpk, ldb, blockIdx.y*128, b1, b2,
              Cout, ldc, KS, out_bf16, smem);
}

// ===========================================================================
// Gates GEMM (packed, gate-interleaved rows, tripled-K) + fused LSTM cell.
// 512 threads, split-K2-in-block.
// ===========================================================================
__device__ void gates_cell_tile(const __hip_bfloat16* Apk, long lda,
                                const __hip_bfloat16* Wpk, long ldw,
                                const float* bpk, float* c_state, float* h_f32,
                                __hip_bfloat16* d1, int d1ld, int d1kp, int d1off,
                                __hip_bfloat16* d2, int d2ld, int d2kp, int d2off,
                                __hip_bfloat16* d3, int d3ld, int d3kp, int d3off,
                                int KS_all, int KS0, int m0, int jb, char* smem)
{
    floatx4 z4 = {0.f,0.f,0.f,0.f};
    floatx4 acc[2][2] = {{z4,z4},{z4,z4}};
    mfma_splitk2(Apk, lda, m0, Wpk + (long)jb*128*ldw, ldw, KS_all, KS0, smem, acc);
    const int tid = threadIdx.x, kg = tid>>8, t2 = tid&255, l = t2&63, w = t2>>6;
    float (*gl)[36] = (float(*)[36])smem;   // 128x36 fp32, overlays kg0 sA/sB (dead)
    if (!kg) {
        for (int i = 0; i < 2; ++i)
          for (int jn = 0; jn < 2; ++jn) {
            int nl = (w*2+jn)*16 + (l&15);
            int mb = i*16 + ((l>>4)<<2);
            *(floatx4*)&gl[nl][mb] = acc[i][jn];
          }
    }
    __syncthreads();
    for (int idx = tid; idx < 1024; idx += 512) {
        int u = idx >> 5, m = idx & 31;
        float g0 = gl[u   ][m] + bpk[jb*128 + u];
        float g1 = gl[32+u][m] + bpk[jb*128 + 32 + u];
        float g2 = gl[64+u][m] + bpk[jb*128 + 64 + u];
        float g3 = gl[96+u][m] + bpk[jb*128 + 96 + u];
        int bg = m0 + m, un = jb*32 + u;
        long ci = (long)bg*512 + un;
        float c2 = sigmoidf_(g1)*c_state[ci] + sigmoidf_(g0)*tanhf(g2);
        float h2 = sigmoidf_(g3)*tanhf(c2);
        c_state[ci] = c2;
        if (h_f32) h_f32[ci] = h2;
        store3(d1, (long)bg*d1ld, d1kp, d1off + un, h2);
        if (d2) store3(d2, (long)bg*d2ld, d2kp, d2off + un, h2);
        if (d3) store3(d3, (long)bg*d3ld, d3kp, d3off + un, h2);
    }
}

// ===========================================================================
// Alignment attention (per-batch block, 512 threads): logits, softmax, sent.
// ===========================================================================
__device__ void align_fn(int b, const float* dp, const float* langpre,
                         const float* hlang, const float* w2,
                         __hip_bfloat16* Ad_p, char* smem)
{
    float* dps    = (float*)smem;     // 512
    float* red    = dps + 512;        // 512
    float* logits = red + 512;        // 32
    float* smv    = logits + 32;      // 32
    float* ssum   = smv + 32;         // 1
    const int tid = threadIdx.x;
    dps[tid] = dp[(long)b*512 + tid];
    __syncthreads();
    {
        int ll = tid >> 4, part = tid & 15;      // 32 logits x 16 parts of 32
        const float* lp = langpre + ((long)b*32 + ll)*512 + part*32;
        const float* dpp = dps + part*32;
        const float* w2p = w2 + part*32;
        float acc = 0.f;
        for (int a = 0; a < 32; ++a)
            acc += tanhf(dpp[a] + lp[a]) * w2p[a];
        red[tid] = acc;
    }
    __syncthreads();
    if ((tid & 15) == 0) {
        float s = 0.f;
        for (int p2 = 0; p2 < 16; ++p2) s += red[tid + p2];
        logits[tid >> 4] = s;
    }
    __syncthreads();
    if (tid == 0) {
        float mx = logits[0];
        for (int i = 1; i < 32; ++i) mx = fmaxf(mx, logits[i]);
        float s = 0.f;
        for (int i = 0; i < 32; ++i) { float e = expf(logits[i]-mx); smv[i]=e; s+=e; }
        ssum[0] = s;
    }
    __syncthreads();
    if (tid < 256) {
        float acc = 0.f;
        const float* hl = hlang + (long)b*32*256 + tid;
        for (int i = 0; i < 32; ++i) acc += smv[i]*hl[(long)i*256];
        store3(Ad_p, (long)b*2688, 896, 104 + tid, acc/ssum[0]);
    }
}

// K_E: blocks 0-63 enc gates (split-K2-in-block); blocks 64-191 alignment
__global__ __launch_bounds__(512)
void enc_align_k(const __hip_bfloat16* Ae_p, const __hip_bfloat16* Wenc,
                 const float* benc, float* c_enc,
                 __hip_bfloat16* Ae_q, __hip_bfloat16* Ahe3,
                 const float* dp, const float* langpre, const float* hlang,
                 const float* w2, __hip_bfloat16* Ad_p)
{
    __shared__ __align__(16) char smem[57344];
    int bid = blockIdx.x;
    if (bid < 64) {
        int m0 = ((bid>>4)&3)*32, jb = bid & 15;
        gates_cell_tile(Ae_p, 3552, Wenc, 3552, benc, c_enc, nullptr,
                        Ae_q, 3552, 1184, 664,  Ahe3, 1536, 512, 0,
                        nullptr, 0, 0, 0,  111, 56, m0, jb, smem);
    } else {
        align_fn(bid-64, dp, langpre, hlang, w2, Ad_p, smem);
    }
}

// K_D: dec gates+cell (split-K2-in-block)
__global__ __launch_bounds__(512)
void dec_k(const __hip_bfloat16* Ad_p, const __hip_bfloat16* Wdec, const float* bdec,
           float* c_dec, float* h_dec,
           __hip_bfloat16* Ae_q, __hip_bfloat16* Ad_q, __hip_bfloat16* Ahd3)
{
    __shared__ __align__(16) char smem[57344];
    int m0 = ((blockIdx.x>>4)&3)*32, jb = blockIdx.x & 15;
    gates_cell_tile(Ad_p, 2688, Wdec, 2688, bdec, c_dec, h_dec,
                    Ae_q, 3552, 1184, 152,  Ad_q, 2688, 896, 360,
                    Ahd3, 1536, 512, 0,  84, 42, m0, jb, smem);
}

// ===========================================================================
// K_M: mu/sigma/q. Wms3 packed interleaved: per 128-row group g (0..1):
//   rows g*128+u : u<64 -> mu[g*64+u], u>=64 -> sig[g*64+(u-64)]  (pad past 100)
// Grid (4 m-tiles, 2 n-groups), 512 threads, split-K2-in-block.
// ===========================================================================
__global__ __launch_bounds__(512)
void musig_k(const __hip_bfloat16* Ahe3, const __hip_bfloat16* Wms3,
             const float* mu_b, const float* sig_b,
             const float* eps, __hip_bfloat16* Ad_p)
{
    __shared__ __align__(16) char smem[57344];
    floatx4 z4 = {0.f,0.f,0.f,0.f};
    floatx4 acc[2][2] = {{z4,z4},{z4,z4}};
    int m0 = blockIdx.x*32, n0 = blockIdx.y*128, base = blockIdx.y*64;
    mfma_splitk2(Ahe3, 1536, m0, Wms3 + (long)n0*1536, 1536, 48, 24, smem, acc);
    const int tid = threadIdx.x, kg = tid>>8, t2 = tid&255, l = t2&63, w = t2>>6;
    float (*gl)[36] = (float(*)[36])smem;   // 128x36
    if (!kg) {
        for (int i = 0; i < 2; ++i)
          for (int jn = 0; jn < 2; ++jn) {
            int nl = (w*2+jn)*16 + (l&15);
            int mb = i*16 + ((l>>4)<<2);
            *(floatx4*)&gl[nl][mb] = acc[i][jn];
          }
    }
    __syncthreads();
    for (int idx = tid; idx < 2048; idx += 512) {
        int u = idx >> 5, m = idx & 31;
        int o = base + u;
        if (o >= 100) continue;
        int bg = m0 + m;
        float mu = gl[u][m] + mu_b[o];
        float sg = expf(gl[64+u][m] + sig_b[o]);
        float q = mu + eps[(long)bg*100 + o]*sg;
        store3(Ad_p, (long)bg*2688, 896, o, q);
    }
}

// ===========================================================================
// Fused 5-param attention head, 512 threads: each thread one k, 8-wave reduce.
// scratch >= 40 floats.
// ===========================================================================
__device__ void attn_params5(const float* hd, const float* attn_W, const float* attn_b,
                             float* sP, float* scratch)
{
    const int tid = threadIdx.x;
    float v = hd[tid];
    float p0 = v*attn_W[tid],      p1 = v*attn_W[512+tid],  p2 = v*attn_W[1024+tid];
    float p3 = v*attn_W[1536+tid], p4 = v*attn_W[2048+tid];
    for (int off = 32; off; off >>= 1) {
        p0 += __shfl_down(p0, off); p1 += __shfl_down(p1, off);
        p2 += __shfl_down(p2, off); p3 += __shfl_down(p3, off);
        p4 += __shfl_down(p4, off);
    }
    if ((tid & 63) == 0) {
        int wv = tid >> 6;
        scratch[wv*5+0]=p0; scratch[wv*5+1]=p1; scratch[wv*5+2]=p2;
        scratch[wv*5+3]=p3; scratch[wv*5+4]=p4;
    }
    __syncthreads();
    if (tid < 5) {
        float s = 0.f;
        for (int wv = 0; wv < 8; ++wv) s += scratch[wv*5+tid];
        sP[tid] = s + attn_b[tid];
    }
    __syncthreads();
}

// ===========================================================================
// Read-attention glimpse (per-batch block, 512 threads)
// ===========================================================================
__device__ void glimpse_fn(int b, const float* x, const float* h_dec,
                           const float* attn_W, const float* attn_b,
                           __hip_bfloat16* Ae_q, char* smem)
{
    float* red = (float*)smem;   // 64 (scratch)
    float* sP  = red + 64;       // 8
    float* Fx  = sP + 8;         // 320
    float* Fy  = Fx + 320;       // 320
    float* denx= Fy + 320;       // 8
    float* deny= denx + 8;       // 8
    float* SFx = deny + 8;       // 8
    float* SFy = SFx + 8;        // 8
    float* tmp1= SFy + 8;        // 960
    const int tid = threadIdx.x;
    attn_params5(h_dec + (long)b*512, attn_W, attn_b, sP, red);
    float gx    = 32.5f*(sP[0]+1.f);
    float gy    = 32.5f*(sP[1]+1.f);
    float s2    = expf(sP[2]);
    float delta = 15.75f*expf(sP[3]);
    if (tid < 320) {
        int i = tid >> 6, a = tid & 63;
        float mux = gx + ((float)i - 3.0f)*delta;
        float muy = gy + ((float)i - 3.0f)*delta;
        float dx = (float)a - mux, dy = (float)a - muy;
        Fx[i*64+a] = expf(-dx*dx/(2.f*s2));
        Fy[i*64+a] = expf(-dy*dy/(2.f*s2));
    }
    __syncthreads();
    if (tid < 10) {
        int i = tid % 5;
        const float* F = (tid < 5) ? (Fx + i*64) : (Fy + i*64);
        float s = 0.f;
        for (int a = 0; a < 64; ++a) s += F[a];
        if (tid < 5) denx[i] = s + 1e-8f; else deny[i] = s + 1e-8f;
    }
    __syncthreads();
    if (tid < 320) {
        int i = tid >> 6, a = tid & 63;
        Fx[i*64+a] /= denx[i];
        Fy[i*64+a] /= deny[i];
    }
    __syncthreads();
    if (tid < 10) {
        int i = tid % 5;
        const float* F = (tid < 5) ? (Fx + i*64) : (Fy + i*64);
        float s = 0.f;
        for (int a = 0; a < 64; ++a) s += F[a];
        if (tid < 5) SFx[i] = s; else SFy[i] = s;
    }
    __syncthreads();
    if (tid < 192) {
        int cc = tid / 64, yy = tid - cc*64;
        const float4* row4 = (const float4*)(x + (long)b*12288 + cc*4096 + yy*64);
        float a0=0,a1=0,a2=0,a3=0,a4=0;
        #pragma unroll
        for (int q4 = 0; q4 < 16; ++q4) {
            float4 v = row4[q4];
            int xx = q4*4;
            a0 += v.x*Fx[xx]     + v.y*Fx[xx+1]     + v.z*Fx[xx+2]     + v.w*Fx[xx+3];
            a1 += v.x*Fx[64+xx]  + v.y*Fx[64+xx+1]  + v.z*Fx[64+xx+2]  + v.w*Fx[64+xx+3];
            a2 += v.x*Fx[128+xx] + v.y*Fx[128+xx+1] + v.z*Fx[128+xx+2] + v.w*Fx[128+xx+3];
            a3 += v.x*Fx[192+xx] + v.y*Fx[192+xx+1] + v.z*Fx[192+xx+2] + v.w*Fx[192+xx+3];
            a4 += v.x*Fx[256+xx] + v.y*Fx[256+xx+1] + v.z*Fx[256+xx+2] + v.w*Fx[256+xx+3];
        }
        tmp1[(cc*64+yy)*5+0]=a0; tmp1[(cc*64+yy)*5+1]=a1; tmp1[(cc*64+yy)*5+2]=a2;
        tmp1[(cc*64+yy)*5+3]=a3; tmp1[(cc*64+yy)*5+4]=a4;
    }
    __syncthreads();
    if (tid < 75) {
        int cc = tid/25, i = (tid/5)%5, j = tid%5;
        float g = 0.f;
        for (int yy = 0; yy < 64; ++yy) g += Fy[i*64+yy]*tmp1[(cc*64+yy)*5 + j];
        float gamma = expf(sP[4]);
        long ro = (long)b*3552;
        store3(Ae_q, ro, 1184, tid,      gamma*g);
        store3(Ae_q, ro, 1184, 75 + tid, gamma*(g - 0.5f*SFy[i]*SFx[j]));
    }
}

// ===========================================================================
// Write head (per-batch block, 512 threads), fp32 throughout
// ===========================================================================
__device__ void write_fn(int b, const float* h_dec,
                         const float* write_W, const float* write_b,
                         const float* attn_W, const float* attn_b,
                         float* outp, char* smem)
{
    float* hs  = (float*)smem;    // 512
    float* red = hs + 512;        // 64 (scratch)
    float* sP  = red + 64;        // 8
    float* w75 = sP + 8;          // 80
    float* Fx  = w75 + 80;        // 320
    float* Fy  = Fx + 320;        // 320
    float* denx= Fy + 320;        // 8
    float* deny= denx + 8;        // 8
    float* t2  = deny + 8;        // 960
    const int tid = threadIdx.x;
    hs[tid] = h_dec[(long)b*512 + tid];
    __syncthreads();
    attn_params5(hs, attn_W, attn_b, sP, red);
    float gx    = 32.5f*(sP[0]+1.f);
    float gy    = 32.5f*(sP[1]+1.f);
    float s2    = expf(sP[2]);
    float delta = 15.75f*expf(sP[3]);
    float inv_g = 1.f/expf(sP[4]);
    if (tid < 75) {
        const float4* w4 = (const float4*)(write_W + (long)tid*512);
        const float4* h4 = (const float4*)hs;
        float acc = 0.f;
        for (int k = 0; k < 128; ++k) {
            float4 wv = w4[k], hv = h4[k];
            acc += wv.x*hv.x + wv.y*hv.y + wv.z*hv.z + wv.w*hv.w;
        }
        w75[tid] = acc + write_b[tid];
    }
    if (tid < 320) {
        int i = tid >> 6, a = tid & 63;
        float mux = gx + ((float)i - 3.0f)*delta;
        float muy = gy + ((float)i - 3.0f)*delta;
        float dx = (float)a - mux, dy = (float)a - muy;
        Fx[i*64+a] = expf(-dx*dx/(2.f*s2));
        Fy[i*64+a] = expf(-dy*dy/(2.f*s2));
    }
    __syncthreads();
    if (tid < 10) {
        int i = tid % 5;
        const float* F = (tid < 5) ? (Fx + i*64) : (Fy + i*64);
        float s = 0.f;
        for (int a = 0; a < 64; ++a) s += F[a];
        if (tid < 5) denx[i] = s + 1e-8f; else deny[i] = s + 1e-8f;
    }
    __syncthreads();
    if (tid < 320) {
        int i = tid >> 6, a = tid & 63;
        Fx[i*64+a] /= denx[i];
        Fy[i*64+a] /= deny[i];
    }
    __syncthreads();
    for (int p = tid; p < 960; p += 512) {
        int cc = p / 320, rem = p - cc*320;
        int i = rem / 64, xx = rem - i*64;
        float acc = 0.f;
        for (int j = 0; j < 5; ++j) acc += w75[cc*25 + i*5 + j]*Fx[j*64+xx];
        t2[(cc*5+i)*64+xx] = acc;
    }
    __syncthreads();
    float* ob = outp + (long)b*12288;
    for (int p = tid; p < 12288; p += 512) {
        int cc = p >> 12, yy = (p >> 6) & 63, xx = p & 63;
        float acc = 0.f;
        for (int i = 0; i < 5; ++i) acc += Fy[i*64+yy]*t2[(cc*5+i)*64+xx];
        ob[p] = acc*inv_g;
    }
}

// K_G: blocks 0-127 glimpse(t+1); 128-143 dp GEMM(t+1, split-K2); 144-271 write(t)
__global__ __launch_bounds__(512)
void wgd_k(const float* x, const float* h_dec,
           const float* attn_W, const float* attn_b,
           const float* write_W, const float* write_b,
           float* outp,
           __hip_bfloat16* Ae_q,
           const __hip_bfloat16* Ahd3, const __hip_bfloat16* W1dec3,
           float* dp)
{
    __shared__ __align__(16) char smem[57344];
    int bid = blockIdx.x;
    if (bid < 128) {
        glimpse_fn(bid, x, h_dec, attn_W, attn_b, Ae_q, smem);
    } else if (bid < 144) {
        int t = bid - 128;
        gemm_tile_sk2(Ahd3, 1536, (t&3)*32, W1dec3, 1536, (t>>2)*128,
                      dp, 512, 48, 24, smem);
    } else {
        if (outp) write_fn(bid-144, h_dec, write_W, write_b, attn_W, attn_b, outp, smem);
    }
}

// ===========================================================================
// Language bi-LSTM: fused over all 32 steps. One block = 2 batches x 1 dir,
// 512 threads; thread = one gate row, Whh row cached in 32 float4 REGISTERS.
// ===========================================================================
__global__ __launch_bounds__(512)
void lang_all_k(const float* xpf, const float* xpb,
                const float* Whh_f, const float* Whh_b,
                float* hlang)
{
    const int pr  = blockIdx.x & 63;      // batch pair
    const int dir = blockIdx.x >> 6;
    const int tid = threadIdx.x;          // gate row 0..511
    const int b0  = pr*2;
    const float* Whh = dir ? Whh_b : Whh_f;
    const float* xps = dir ? xpb : xpf;
    __shared__ __align__(16) float hs[2][128];
    __shared__ float gs[2][512];
    float4 wr[32];
    {
        const float4* w4 = (const float4*)(Whh + (long)tid*128);
        #pragma unroll
        for (int k = 0; k < 32; ++k) wr[k] = w4[k];
    }
    if (tid < 256) hs[tid>>7][tid&127] = 0.f;
    float cst = 0.f;
    __syncthreads();
    for (int s = 0; s < 32; ++s) {
        const int l = dir ? (31 - s) : s;
        const float4* h40 = (const float4*)hs[0];
        const float4* h41 = (const float4*)hs[1];
        float a0 = 0.f, a1 = 0.f;
        #pragma unroll
        for (int k = 0; k < 32; ++k) {
            float4 wv = wr[k], h0 = h40[k], h1 = h41[k];
            a0 += wv.x*h0.x + wv.y*h0.y + wv.z*h0.z + wv.w*h0.w;
            a1 += wv.x*h1.x + wv.y*h1.y + wv.z*h1.z + wv.w*h1.w;
        }
        gs[0][tid] = a0 + xps[((long)b0*32 + l)*512 + tid];
        gs[1][tid] = a1 + xps[((long)(b0+1)*32 + l)*512 + tid];
        __syncthreads();   // gs ready; all hs reads of this step done
        if (tid < 256) {
            int bb = tid >> 7, u = tid & 127;
            float c2 = sigmoidf_(gs[bb][128+u])*cst + sigmoidf_(gs[bb][u])*tanhf(gs[bb][256+u]);
            float h2 = sigmoidf_(gs[bb][384+u])*tanhf(c2);
            cst = c2;
            hlang[((long)(b0+bb)*32 + l)*256 + dir*128 + u] = h2;
            hs[bb][u] = h2;
        }
        __syncthreads();   // hs(s+1) ready
    }
}

// ===========================================================================
// Packing kernels: fp32 -> tripled split-bf16. 2D grid (y = row) — no
// per-element integer division.
// ===========================================================================
__global__ void pack_a3_k(__hip_bfloat16* dst, int KP,
                          const float* src, int ld, int K1)
{
    int k3 = blockIdx.x*256 + threadIdx.x;
    int K3 = 3*KP;
    if (k3 >= K3) return;
    long n = blockIdx.y;
    int plane = (k3 >= KP) + (k3 >= 2*KP);
    int k = k3 - plane*KP;
    float v = (k < K1) ? src[n*ld + k] : 0.f;
    __hip_bfloat16 hi = __float2bfloat16(v);
    float lo = v - __bfloat162float(hi);
    dst[n*K3 + k3] = (plane==1) ? __float2bfloat16(lo) : hi;
}

__global__ void pack_w3_k(__hip_bfloat16* dst, int KP,
                          const float* src, int ld, int K1)
{
    int k3 = blockIdx.x*256 + threadIdx.x;
    int K3 = 3*KP;
    if (k3 >= K3) return;
    long n = blockIdx.y;
    int plane = (k3 >= KP) + (k3 >= 2*KP);
    int k = k3 - plane*KP;
    float v = (k < K1) ? src[n*ld + k] : 0.f;
    __hip_bfloat16 hi = __float2bfloat16(v);
    float lo = v - __bfloat162float(hi);
    dst[n*K3 + k3] = (plane==2) ? __float2bfloat16(lo) : hi;
}

__global__ void pack_gates3_k(__hip_bfloat16* dst, int KP,
                              const float* Wih, int ldih, int K1, int off2, int K2, int off3,
                              const float* Whh)
{
    int k3 = blockIdx.x*256 + threadIdx.x;
    int K3 = 3*KP;
    if (k3 >= K3) return;
    int p = blockIdx.y;
    int plane = (k3 >= KP) + (k3 >= 2*KP);
    int k = k3 - plane*KP;
    int j = p >> 7, g = (p>>5)&3, uu = p&31;
    int n = g*512 + j*32 + uu;
    float v = 0.f;
    if (k < K1)                          v = Wih[(long)n*ldih + k];
    else if (k >= off2 && k < off2+K2)   v = Wih[(long)n*ldih + K1 + (k-off2)];
    else if (k >= off3 && k < off3+512)  v = Whh[(long)n*512 + (k-off3)];
    __hip_bfloat16 hi = __float2bfloat16(v);
    float lo = v - __bfloat162float(hi);
    dst[(long)p*K3 + k3] = (plane==2) ? __float2bfloat16(lo) : hi;
}

__global__ void pack_gbias_k(float* dst, const float* bih, const float* bhh)
{
    int p = blockIdx.x*256 + threadIdx.x;
    if (p >= 2048) return;
    int j = p >> 7, g = (p>>5)&3, uu = p&31;
    int n = g*512 + j*32 + uu;
    dst[p] = bih[n] + bhh[n];
}

// Interleaved mu/sig pack: row p: group g=p>>7, u=p&127;
//   u<64 -> mu[g*64+u], u>=64 -> sig[g*64+(u-64)]; pad when index >= 100.
__global__ void pack_musig3_k(__hip_bfloat16* dst, const float* mu_W, const float* sig_W)
{
    int k3 = blockIdx.x*256 + threadIdx.x;
    if (k3 >= 1536) return;
    int p = blockIdx.y;
    int plane = k3 >> 9, k = k3 & 511;
    int u = p & 127, base = (p >> 7)*64;
    int z = base + (u & 63);
    const float* W = (u < 64) ? mu_W : sig_W;
    float v = (z < 100) ? W[(long)z*512 + k] : 0.f;
    __hip_bfloat16 hi = __float2bfloat16(v);
    float lo = v - __bfloat162float(hi);
    dst[(long)p*1536 + k3] = (plane==2) ? __float2bfloat16(lo) : hi;
}

// ===========================================================================
extern "C" void kernel_launch(void* const* d_in, const int* in_sizes, int n_in,
                              void* d_out, int out_size, void* d_ws, size_t ws_size,
                              hipStream_t stream)
{
    const float* x        = (const float*)d_in[0];
    const float* y        = (const float*)d_in[1];
    const float* eps_q    = (const float*)d_in[2];
    const float* enc_Wih  = (const float*)d_in[3];
    const float* enc_Whh  = (const float*)d_in[4];
    const float* enc_bih  = (const float*)d_in[5];
    const float* enc_bhh  = (const float*)d_in[6];
    const float* dec_Wih  = (const float*)d_in[7];
    const float* dec_Whh  = (const float*)d_in[8];
    const float* dec_bih  = (const float*)d_in[9];
    const float* dec_bhh  = (const float*)d_in[10];
    const float* mu_W     = (const float*)d_in[11];
    const float* mu_b     = (const float*)d_in[12];
    const float* sig_W    = (const float*)d_in[13];
    const float* sig_b    = (const float*)d_in[14];
    const float* write_W  = (const float*)d_in[15];
    const float* write_b  = (const float*)d_in[16];
    const float* align_W1 = (const float*)d_in[17];
    const float* align_b1 = (const float*)d_in[18];
    const float* align_w2 = (const float*)d_in[19];
    const float* attn_W   = (const float*)d_in[20];
    const float* attn_b   = (const float*)d_in[21];
    const float* lf_Wih   = (const float*)d_in[22];
    const float* lf_Whh   = (const float*)d_in[23];
    const float* lf_bih   = (const float*)d_in[24];
    const float* lf_bhh   = (const float*)d_in[25];
    const float* lb_Wih   = (const float*)d_in[26];
    const float* lb_Whh   = (const float*)d_in[27];
    const float* lb_bih   = (const float*)d_in[28];
    const float* lb_bhh   = (const float*)d_in[29];
    float* out = (float*)d_out;

    float* ws = (float*)d_ws;
    size_t off = 0;
    auto alloc = [&](size_t n){ float* p = ws + off; off += n; return p; };

    // ---- zeroed region ----
    float* Aenc0f = alloc(227328);   // 128x3552 bf16
    float* Aenc1f = alloc(227328);
    float* Adec0f = alloc(172032);   // 128x2688 bf16
    float* Adec1f = alloc(172032);
    float* Ahd3f  = alloc(98304);    // 128x1536 bf16 (h_dec split, for dp GEMM)
    float* Ahe3f  = alloc(98304);    // 128x1536 bf16 (h_enc split, for musig)
    float* c_enc  = alloc(65536);
    float* c_dec  = alloc(65536);
    float* h_dec  = alloc(65536);
    size_t zero_floats = off;
    // ---- persistent ----
    float* dpb      = alloc(65536);     // 128x512 fp32
    float* hlangf   = alloc(1048576);   // 4096x256 fp32
    float* hlang3f  = alloc(1572864);   // 4096x768 bf16 tripled
    float* langpre  = alloc(2097152);   // 4096x512 fp32
    float* W1lang3f = alloc(196608);    // 512x768 bf16
    float* W1dec3f  = alloc(393216);    // 512x1536 bf16
    // ---- shared region (phase1 / phase2 overlap) ----
    float* shared = alloc(6651904);
    // phase1 layout
    float* y3f   = shared;               // 4096x960 bf16  = 1966080 f
    float* Wlf3f = shared + 1966080;     // 512x960 bf16   = 245760 f
    float* Wlb3f = Wlf3f + 245760;
    float* xpf   = Wlb3f + 245760;       // 4096x512 fp32  = 2097152 f
    float* xpb   = xpf + 2097152;
    // phase2 layout (same region, used after lang steps)
    float* Wenc3f = shared;              // 2048x3552 bf16 = 3637248 f
    float* Wdec3f = Wenc3f + 3637248;    // 2048x2688 bf16 = 2752512 f
    float* Wms3f  = Wdec3f + 2752512;    // 256x1536 bf16  = 196608 f
    float* benc   = Wms3f + 196608;      // 2048 f
    float* bdec   = benc + 2048;         // 2048 f

    __hip_bfloat16* Aenc0 = (__hip_bfloat16*)Aenc0f;
    __hip_bfloat16* Aenc1 = (__hip_bfloat16*)Aenc1f;
    __hip_bfloat16* Adec0 = (__hip_bfloat16*)Adec0f;
    __hip_bfloat16* Adec1 = (__hip_bfloat16*)Adec1f;
    __hip_bfloat16* Ahd3  = (__hip_bfloat16*)Ahd3f;
    __hip_bfloat16* Ahe3  = (__hip_bfloat16*)Ahe3f;
    __hip_bfloat16* hlang3= (__hip_bfloat16*)hlang3f;
    __hip_bfloat16* W1lang3=(__hip_bfloat16*)W1lang3f;
    __hip_bfloat16* W1dec3= (__hip_bfloat16*)W1dec3f;
    __hip_bfloat16* y3    = (__hip_bfloat16*)y3f;
    __hip_bfloat16* Wlf3  = (__hip_bfloat16*)Wlf3f;
    __hip_bfloat16* Wlb3  = (__hip_bfloat16*)Wlb3f;
    __hip_bfloat16* Wenc3 = (__hip_bfloat16*)Wenc3f;
    __hip_bfloat16* Wdec3 = (__hip_bfloat16*)Wdec3f;
    __hip_bfloat16* Wms3  = (__hip_bfloat16*)Wms3f;

    hipMemsetAsync(ws, 0, zero_floats*sizeof(float), stream);

    // ---- phase 1: language bi-LSTM (fp32 recurrence, split-bf16 GEMMs) ----
    pack_a3_k<<<dim3(4,4096),256,0,stream>>>(y3, 320, y, 300, 300);
    pack_w3_k<<<dim3(4,512),256,0,stream>>>(Wlf3, 320, lf_Wih, 300, 300);
    pack_w3_k<<<dim3(4,512),256,0,stream>>>(Wlb3, 320, lb_Wih, 300, 300);
    pack_w3_k<<<dim3(3,512),256,0,stream>>>(W1lang3, 256, align_W1+512, 768, 256);
    pack_w3_k<<<dim3(6,512),256,0,stream>>>(W1dec3, 512, align_W1, 768, 512);
    gemm_mfma_k<<<dim3(128,4),256,0,stream>>>(y3, 960, Wlf3, 960, lf_bih, lf_bhh, xpf, 512, 30, 0);
    gemm_mfma_k<<<dim3(128,4),256,0,stream>>>(y3, 960, Wlb3, 960, lb_bih, lb_bhh, xpb, 512, 30, 0);
    lang_all_k<<<128,512,0,stream>>>(xpf, xpb, lf_Whh, lb_Whh, hlangf);
    pack_a3_k<<<dim3(3,4096),256,0,stream>>>(hlang3, 256, hlangf, 256, 256);
    gemm_mfma_k<<<dim3(128,4),256,0,stream>>>(hlang3, 768, W1lang3, 768, align_b1, nullptr, langpre, 512, 24, 0);

    // ---- phase 2 weight packs (shared region reuse: phase1 buffers dead) ----
    pack_gates3_k<<<dim3(42,2048),256,0,stream>>>(Wenc3, 1184, enc_Wih, 662, 150, 152, 512, 664, enc_Whh);
    pack_gates3_k<<<dim3(32,2048),256,0,stream>>>(Wdec3, 896, dec_Wih, 356, 100, 104, 256, 360, dec_Whh);
    pack_gbias_k<<<8,256,0,stream>>>(benc, enc_bih, enc_bhh);
    pack_gbias_k<<<8,256,0,stream>>>(bdec, dec_bih, dec_bhh);
    pack_musig3_k<<<dim3(6,256),256,0,stream>>>(Wms3, mu_W, sig_W);

    // ---- priming: glimpse + dp for t=0 (h_dec = 0, Ahd3 = 0 -> dp = 0) ----
    wgd_k<<<272,512,0,stream>>>(x, h_dec, attn_W, attn_b, write_W, write_b,
                                nullptr, Aenc0, Ahd3, W1dec3, dpb);

    for (int t = 0; t < 32; ++t) {
        int p = t & 1;
        __hip_bfloat16* Ae_p = p ? Aenc1 : Aenc0;
        __hip_bfloat16* Ae_q = p ? Aenc0 : Aenc1;
        __hip_bfloat16* Ad_p = p ? Adec1 : Adec0;
        __hip_bfloat16* Ad_q = p ? Adec0 : Adec1;
        enc_align_k<<<192,512,0,stream>>>(Ae_p, Wenc3, benc, c_enc, Ae_q, Ahe3,
                                          dpb, langpre, hlangf, align_w2, Ad_p);
        musig_k<<<dim3(4,2),512,0,stream>>>(Ahe3, Wms3, mu_b, sig_b,
                                            eps_q + (long)t*12800, Ad_p);
        dec_k<<<64,512,0,stream>>>(Ad_p, Wdec3, bdec, c_dec, h_dec, Ae_q, Ad_q, Ahd3);
        wgd_k<<<272,512,0,stream>>>(x, h_dec, attn_W, attn_b, write_W, write_b,
                                    out + (long)t*128*12288, Ae_q, Ahd3, W1dec3, dpb);
    }
}